// Round 1
// baseline (477.666 us; speedup 1.0000x reference)
//
#include <hip/hip_runtime.h>
#include <cfloat>
#include <cmath>

// Problem constants (fixed by the reference setup).
#define BB 64      // batch
#define NN 32768   // predictions
#define CC 2       // classes
#define KK 10      // GT slots
#define TPB 1024   // threads per block (16 waves)
#define NWAVE (TPB / 64)
#define VLARGE 1.0e6

__device__ __forceinline__ double dsig(float x) {
    return 1.0 / (1.0 + exp(-(double)x));
}
__device__ __forceinline__ double dsoftplus(double x) {
    // log1p(exp(x)) stable form: max(x,0) + log1p(exp(-|x|))
    return fmax(x, 0.0) + log1p(exp(-fabs(x)));
}

// Block-wide argmin of (v, c), lexicographic: smaller v wins, ties -> smaller c.
// Result valid in thread 0 (lane 0 of wave 0).
__device__ void block_minloc(double& v, int& c, double* red_v, int* red_c) {
    const int lane = threadIdx.x & 63;
    const int wid  = threadIdx.x >> 6;
    for (int off = 32; off > 0; off >>= 1) {
        double ov = __shfl_down(v, off, 64);
        int    oc = __shfl_down(c, off, 64);
        if (ov < v || (ov == v && oc < c)) { v = ov; c = oc; }
    }
    if (lane == 0) { red_v[wid] = v; red_c[wid] = c; }
    __syncthreads();
    if (wid == 0) {
        if (lane < NWAVE) { v = red_v[lane]; c = red_c[lane]; }
        else              { v = DBL_MAX;     c = 0x7fffffff;  }
        for (int off = 32; off > 0; off >>= 1) {
            double ov = __shfl_down(v, off, 64);
            int    oc = __shfl_down(c, off, 64);
            if (ov < v || (ov == v && oc < c)) { v = ov; c = oc; }
        }
    }
    __syncthreads();  // protect red_v/red_c reuse by next call
}

__global__ __launch_bounds__(TPB)
void match_loss_kernel(const float* __restrict__ p_start,
                       const float* __restrict__ p_end,
                       const float* __restrict__ p_cls,
                       const float* __restrict__ p_conf,
                       const float* __restrict__ gt,
                       double* __restrict__ partials) {
    const int b = blockIdx.x;
    const float* ps  = p_start + (size_t)b * NN;
    const float* pe  = p_end   + (size_t)b * NN;
    const float* pc  = p_cls   + (size_t)b * NN * CC;
    const float* pcf = p_conf  + (size_t)b * NN;

    __shared__ double s_fs[KK], s_fe[KK];
    __shared__ int    s_cls[KK], s_pres[KK];
    __shared__ double s_rv[KK];      // per-row current min value
    __shared__ int    s_rc[KK];      // per-row current min col
    __shared__ int    s_rowact[KK];  // row still unmatched
    __shared__ int    s_ucol[KK];    // used (masked) columns, in pick order
    __shared__ int    s_prow[KK], s_pcol[KK], s_pvalid[KK];
    __shared__ int    s_resc[KK];    // rows needing rescan this step
    __shared__ int    s_nresc;
    __shared__ double red_v[NWAVE];
    __shared__ int    red_c[NWAVE];

    const int tid = threadIdx.x;

    // ---- Phase 0: build targets (fs, fe, class, presence) ----
    if (tid < KK) {
        float f0 = gt[((size_t)b * KK + tid) * 3 + 0];
        float f1 = gt[((size_t)b * KK + tid) * 3 + 1];
        float f2 = gt[((size_t)b * KK + tid) * 3 + 2];
        int pres = !(isnan(f0) || isnan(f1) || isnan(f2));
        if (isnan(f0)) f0 = 0.0f;
        if (isnan(f1)) f1 = 0.0f;
        if (isnan(f2)) f2 = 0.0f;
        s_pres[tid] = pres;
        s_fs[tid] = (double)f0;
        s_fe[tid] = (double)f1;
        int ci = (int)f2;
        ci = ci < 0 ? 0 : (ci > CC - 1 ? CC - 1 : ci);
        s_cls[tid] = ci;
        s_rowact[tid] = 1;
    }
    __syncthreads();

    // ---- Phase 1: fused per-row minima over all N columns (one pass) ----
    double lv[KK];
    int    lc[KK];
    for (int k = 0; k < KK; k++) { lv[k] = DBL_MAX; lc[k] = 0x7fffffff; }

    for (int n = tid; n < NN; n += TPB) {
        const double s  = dsig(ps[n]);
        const double e  = dsig(pe[n]);
        const double c0 = dsig(pc[2 * n]);
        const double c1 = dsig(pc[2 * n + 1]);
        const double q  = c0 * c0 + c1 * c1;
        for (int k = 0; k < KK; k++) {
            double cost;
            if (s_pres[k]) {
                const double d0 = s - s_fs[k];
                const double d1 = e - s_fe[k];
                const double sc = (s_cls[k] == 0) ? c0 : c1;
                cost = (d0 * d0 + d1 * d1) + ((q - 2.0 * sc) + 1.0);
            } else {
                cost = VLARGE;
            }
            // strict < keeps the lowest column (n ascends within a thread)
            if (cost < lv[k]) { lv[k] = cost; lc[k] = n; }
        }
    }
    for (int k = 0; k < KK; k++) {
        double v = lv[k];
        int    c = lc[k];
        block_minloc(v, c, red_v, red_c);
        if (tid == 0) { s_rv[k] = v; s_rc[k] = c; }
    }
    __syncthreads();

    // ---- Phase 2: greedy one-to-one matching (K steps) ----
    const double half_vl = VLARGE * 0.5;
    for (int step = 0; step < KK; step++) {
        if (tid == 0) {
            // global argmin over active rows; ties -> lowest row (row-major flat argmin)
            double bv = DBL_MAX;
            int    br = 0;
            for (int k = 0; k < KK; k++) {
                if (s_rowact[k] && s_rv[k] < bv) { bv = s_rv[k]; br = k; }
            }
            const int bc = s_rc[br];
            s_prow[step]   = br;
            s_pcol[step]   = bc;
            s_pvalid[step] = (bv < half_vl) ? 1 : 0;
            s_rowact[br]   = 0;
            s_ucol[step]   = bc;
            int nr = 0;
            for (int k = 0; k < KK; k++)
                if (s_rowact[k] && s_rc[k] == bc) s_resc[nr++] = k;
            s_nresc = nr;
        }
        __syncthreads();

        const int nresc = s_nresc;
        for (int i = 0; i < nresc; i++) {
            const int r = s_resc[i];
            const double fs_r = s_fs[r], fe_r = s_fe[r];
            const int cls_r = s_cls[r], pres_r = s_pres[r];
            double v = DBL_MAX;
            int    c = 0x7fffffff;
            for (int n = tid; n < NN; n += TPB) {
                bool used = false;
                for (int j = 0; j <= step; j++)
                    if (s_ucol[j] == n) used = true;
                if (used) continue;
                double cost;
                if (pres_r) {
                    const double s  = dsig(ps[n]);
                    const double e  = dsig(pe[n]);
                    const double c0 = dsig(pc[2 * n]);
                    const double c1 = dsig(pc[2 * n + 1]);
                    const double q  = c0 * c0 + c1 * c1;
                    const double d0 = s - fs_r;
                    const double d1 = e - fe_r;
                    const double sc = (cls_r == 0) ? c0 : c1;
                    cost = (d0 * d0 + d1 * d1) + ((q - 2.0 * sc) + 1.0);
                } else {
                    cost = VLARGE;
                }
                if (cost < v) { v = cost; c = n; }
            }
            block_minloc(v, c, red_v, red_c);
            if (tid == 0) { s_rv[r] = v; s_rc[r] = c; }
            __syncthreads();
        }
        __syncthreads();  // publish this step's state before next pick
    }

    // ---- Phase 3: losses over matched pairs (tiny; thread 0) ----
    if (tid == 0) {
        double loc_s = 0.0, bce_s = 0.0, conf_s = 0.0, m = 0.0;
        for (int stp = 0; stp < KK; stp++) {
            if (!s_pvalid[stp]) continue;
            const int r    = s_prow[stp];
            const int cidx = s_pcol[stp];
            const double ss = dsig(ps[cidx]);
            const double se = dsig(pe[cidx]);
            const double gs = s_fs[r], ge = s_fe[r];
            const double d0 = ss - gs, d1 = se - ge;
            loc_s += d0 * d0 + d1 * d1;

            const double l0 = (double)pc[2 * cidx];
            const double l1 = (double)pc[2 * cidx + 1];
            const double y0 = (s_cls[r] == 0) ? 1.0 : 0.0;
            const double y1 = 1.0 - y0;
            bce_s += y0 * dsoftplus(-l0) + (1.0 - y0) * dsoftplus(l0)
                   + y1 * dsoftplus(-l1) + (1.0 - y1) * dsoftplus(l1);

            const double a1 = fmin(ss, se), b1 = fmax(ss, se);
            const double a2 = fmin(gs, ge), b2 = fmax(gs, ge);
            const double inter = fmax(0.0, fmin(b1, b2) - fmax(a1, a2));
            const double uni   = fmax(1e-8, fmax(b1, b2) - fmin(a1, a2));
            const double iou   = inter / uni;
            const double dcf   = dsig(pcf[cidx]) - iou;
            conf_s += dcf * dcf;
            m += 1.0;
        }
        partials[b * 4 + 0] = loc_s;
        partials[b * 4 + 1] = bce_s;
        partials[b * 4 + 2] = conf_s;
        partials[b * 4 + 3] = m;
    }
}

__global__ void finalize_kernel(const double* __restrict__ partials,
                                float* __restrict__ out, int out_size) {
    const int t = threadIdx.x;  // 64 threads = 1 wave, one per batch
    for (int i = t; i < out_size; i += 64) out[i] = 0.0f;
    double s = partials[t * 4 + 0] + partials[t * 4 + 1] + partials[t * 4 + 2];
    double m = partials[t * 4 + 3];
    for (int off = 32; off > 0; off >>= 1) {
        s += __shfl_down(s, off, 64);
        m += __shfl_down(m, off, 64);
    }
    if (t == 0) {
        const double total = s / (m + 1e-8);
        out[0] = (float)(m > 0.0 ? total : 0.0);
    }
}

extern "C" void kernel_launch(void* const* d_in, const int* in_sizes, int n_in,
                              void* d_out, int out_size, void* d_ws, size_t ws_size,
                              hipStream_t stream) {
    const float* p_start = (const float*)d_in[0];  // (B, N)
    const float* p_end   = (const float*)d_in[1];  // (B, N)
    const float* p_cls   = (const float*)d_in[2];  // (B, N, C)
    const float* p_conf  = (const float*)d_in[3];  // (B, N)
    const float* gt      = (const float*)d_in[4];  // (B, K, 3)
    double* partials = (double*)d_ws;              // B*4 doubles

    match_loss_kernel<<<BB, TPB, 0, stream>>>(p_start, p_end, p_cls, p_conf, gt, partials);
    finalize_kernel<<<1, 64, 0, stream>>>(partials, (float*)d_out, out_size);
}

// Round 2
// 179.747 us; speedup vs baseline: 2.6574x; 2.6574x over previous
//
#include <hip/hip_runtime.h>
#include <cfloat>
#include <cmath>

// Problem constants (fixed by the reference setup).
#define BB 64       // batch
#define NN 32768    // predictions
#define CC 2        // classes
#define KK 10       // GT slots
#define S_SL 32     // slices of N
#define SLICE (NN / S_SL)   // 1024 columns per slice
#define TPA 256     // threads for scan kernel
#define TPM 256     // threads for match kernel
#define VLARGE 1.0e6

__device__ __forceinline__ float  sigf(float x)  { return 1.0f / (1.0f + expf(-x)); }
__device__ __forceinline__ double dsig(float x)  { return 1.0 / (1.0 + exp(-(double)x)); }
__device__ __forceinline__ double dsoftplus(double x) {
    return fmax(x, 0.0) + log1p(exp(-fabs(x)));
}
__device__ __forceinline__ bool lexlt_f(float va, int ca, float vb, int cb) {
    return va < vb || (va == vb && ca < cb);
}
__device__ __forceinline__ bool lexlt_d(double va, int ca, double vb, int cb) {
    return va < vb || (va == vb && ca < cb);
}

// merge two lex-sorted top-2 lists -> top-2
__device__ __forceinline__ void merge_top2(float& a1, int& ac1, float& a2, int& ac2,
                                           float b1, int bc1, float b2, int bc2) {
    float nv1, nv2; int nc1, nc2;
    if (lexlt_f(a1, ac1, b1, bc1)) {
        nv1 = a1; nc1 = ac1;
        if (lexlt_f(a2, ac2, b1, bc1)) { nv2 = a2; nc2 = ac2; }
        else                           { nv2 = b1; nc2 = bc1; }
    } else {
        nv1 = b1; nc1 = bc1;
        if (lexlt_f(b2, bc2, a1, ac1)) { nv2 = b2; nc2 = bc2; }
        else                           { nv2 = a1; nc2 = ac1; }
    }
    a1 = nv1; ac1 = nc1; a2 = nv2; ac2 = nc2;
}

// ---------------- Kernel A: wide f32 scan, per-row top-2 per slice ----------------
__global__ __launch_bounds__(TPA)
void scan_kernel(const float* __restrict__ p_start, const float* __restrict__ p_end,
                 const float* __restrict__ p_cls, const float* __restrict__ gt,
                 int4* __restrict__ cand) {
    const int sl  = blockIdx.x;   // slice
    const int b   = blockIdx.y;   // batch
    const int tid = threadIdx.x;
    const float*  ps  = p_start + (size_t)b * NN;
    const float*  pe  = p_end   + (size_t)b * NN;
    const float2* pc2 = (const float2*)(p_cls + (size_t)b * NN * CC);

    // row constants in REGISTERS (round-1 kept them in LDS -> per-iter reloads)
    float rfs[KK], rfe[KK], rabs[KK]; int rcl[KK];
    #pragma unroll
    for (int k = 0; k < KK; k++) {
        float f0 = gt[((size_t)b * KK + k) * 3 + 0];
        float f1 = gt[((size_t)b * KK + k) * 3 + 1];
        float f2 = gt[((size_t)b * KK + k) * 3 + 2];
        bool pres = !(isnan(f0) || isnan(f1) || isnan(f2));
        if (isnan(f0)) f0 = 0.0f;
        if (isnan(f1)) f1 = 0.0f;
        if (isnan(f2)) f2 = 0.0f;
        int ci = (int)f2; ci = ci < 0 ? 0 : (ci > CC - 1 ? CC - 1 : ci);
        rfs[k] = f0; rfe[k] = f1; rcl[k] = ci; rabs[k] = pres ? 0.0f : 1.0f;
    }

    float v1[KK], v2[KK]; int c1[KK], c2[KK];
    #pragma unroll
    for (int k = 0; k < KK; k++) { v1[k] = FLT_MAX; v2[k] = FLT_MAX; c1[k] = 0x7fffffff; c2[k] = 0x7fffffff; }

    const int base = sl * SLICE;
    for (int i = tid; i < SLICE; i += TPA) {
        const int n = base + i;
        const float s  = sigf(ps[n]);
        const float e  = sigf(pe[n]);
        const float2 cc = pc2[n];
        const float q0 = sigf(cc.x), q1 = sigf(cc.y);
        const float q  = q0 * q0 + q1 * q1 + 1.0f;
        #pragma unroll
        for (int k = 0; k < KK; k++) {
            const float d0 = s - rfs[k], d1 = e - rfe[k];
            const float sc = (rcl[k] == 0) ? q0 : q1;
            float cost = d0 * d0 + d1 * d1 + (q - 2.0f * sc);
            if (rabs[k] != 0.0f) cost = (float)VLARGE;
            if (lexlt_f(cost, n, v2[k], c2[k])) {
                if (lexlt_f(cost, n, v1[k], c1[k])) { v2[k] = v1[k]; c2[k] = c1[k]; v1[k] = cost; c1[k] = n; }
                else                                { v2[k] = cost; c2[k] = n; }
            }
        }
    }

    // wave butterfly reduce (top-2 merge), then cross-wave via LDS
    #pragma unroll
    for (int off = 1; off < 64; off <<= 1) {
        #pragma unroll
        for (int k = 0; k < KK; k++) {
            float ov1 = __shfl_xor(v1[k], off, 64); int oc1 = __shfl_xor(c1[k], off, 64);
            float ov2 = __shfl_xor(v2[k], off, 64); int oc2 = __shfl_xor(c2[k], off, 64);
            merge_top2(v1[k], c1[k], v2[k], c2[k], ov1, oc1, ov2, oc2);
        }
    }
    __shared__ float sv1[TPA / 64][KK], sv2[TPA / 64][KK];
    __shared__ int   sc1[TPA / 64][KK], sc2[TPA / 64][KK];
    const int wid = tid >> 6, lane = tid & 63;
    if (lane == 0) {
        #pragma unroll
        for (int k = 0; k < KK; k++) { sv1[wid][k] = v1[k]; sc1[wid][k] = c1[k]; sv2[wid][k] = v2[k]; sc2[wid][k] = c2[k]; }
    }
    __syncthreads();
    if (tid < KK) {
        const int k = tid;
        float m1 = sv1[0][k], m2 = sv2[0][k]; int mc1 = sc1[0][k], mc2 = sc2[0][k];
        #pragma unroll
        for (int w = 1; w < TPA / 64; w++)
            merge_top2(m1, mc1, m2, mc2, sv1[w][k], sc1[w][k], sv2[w][k], sc2[w][k]);
        int4 pk;
        pk.x = __float_as_int(m1); pk.y = mc1;
        pk.z = __float_as_int(m2); pk.w = mc2;
        cand[((size_t)b * S_SL + sl) * KK + k] = pk;
    }
}

// ---------------- Kernel B: f64 candidate eval + greedy matching + losses ----------------
__global__ __launch_bounds__(TPM)
void match_kernel(const float* __restrict__ p_start, const float* __restrict__ p_end,
                  const float* __restrict__ p_cls, const float* __restrict__ p_conf,
                  const float* __restrict__ gt, const int4* __restrict__ cand,
                  double* __restrict__ partials) {
    const int b = blockIdx.x, tid = threadIdx.x, lane = tid & 63, wid = tid >> 6;
    const float* ps  = p_start + (size_t)b * NN;
    const float* pe  = p_end   + (size_t)b * NN;
    const float* pc  = p_cls   + (size_t)b * NN * CC;
    const float* pcf = p_conf  + (size_t)b * NN;

    __shared__ double cv[KK][2 * S_SL];
    __shared__ int    ccol[KK][2 * S_SL];
    __shared__ double g_fs[KK], g_fe[KK];
    __shared__ int    g_cls[KK], g_pres[KK], g_act[KK];
    __shared__ double g_rv[KK]; __shared__ int g_rc[KK];
    __shared__ int    prow[KK], pcol[KK], pvalid[KK], consumed[KK];
    __shared__ int    dlist[KK], rlist_r[KK], rlist_s[KK];
    __shared__ int    s_ndirty, s_nresc;
    __shared__ float  w_v1[TPM / 64], w_v2[TPM / 64];
    __shared__ int    w_c1[TPM / 64], w_c2[TPM / 64];
    __shared__ double l_loc[KK], l_bce[KK], l_conf[KK], l_m[KK];

    if (tid < KK) {
        float f0 = gt[((size_t)b * KK + tid) * 3 + 0];
        float f1 = gt[((size_t)b * KK + tid) * 3 + 1];
        float f2 = gt[((size_t)b * KK + tid) * 3 + 2];
        int pres = !(isnan(f0) || isnan(f1) || isnan(f2));
        if (isnan(f0)) f0 = 0.0f;
        if (isnan(f1)) f1 = 0.0f;
        if (isnan(f2)) f2 = 0.0f;
        int ci = (int)f2; ci = ci < 0 ? 0 : (ci > CC - 1 ? CC - 1 : ci);
        g_fs[tid] = (double)f0; g_fe[tid] = (double)f1;
        g_cls[tid] = ci; g_pres[tid] = pres; g_act[tid] = 1;
    }
    __syncthreads();

    // f64 evaluation of all K * 2S candidates
    for (int idx = tid; idx < KK * 2 * S_SL; idx += TPM) {
        const int r = idx >> 6;         // 2*S_SL == 64
        const int j = idx & 63;
        const int sl = j >> 1, which = j & 1;
        int4 pk = cand[((size_t)b * S_SL + sl) * KK + r];
        const int col = which ? pk.w : pk.y;
        double cost;
        if (!g_pres[r]) {
            cost = VLARGE;
        } else {
            const double s  = dsig(ps[col]);
            const double e  = dsig(pe[col]);
            const double q0 = dsig(pc[2 * col]);
            const double q1 = dsig(pc[2 * col + 1]);
            const double d0 = s - g_fs[r], d1 = e - g_fe[r];
            const double sc = (g_cls[r] == 0) ? q0 : q1;
            cost = d0 * d0 + d1 * d1 + (q0 * q0 + q1 * q1 - 2.0 * sc + 1.0);
        }
        cv[r][j] = cost; ccol[r][j] = col;
    }
    __syncthreads();

    // initial per-row min over 64 candidates (wave 0, lex)
    if (wid == 0) {
        for (int r = 0; r < KK; r++) {
            double v = cv[r][lane]; int c = ccol[r][lane];
            #pragma unroll
            for (int off = 1; off < 64; off <<= 1) {
                double ov = __shfl_xor(v, off, 64); int oc = __shfl_xor(c, off, 64);
                if (lexlt_d(ov, oc, v, c)) { v = ov; c = oc; }
            }
            if (lane == 0) { g_rv[r] = v; g_rc[r] = c; }
        }
    }
    __syncthreads();

    // greedy matching, K steps
    for (int step = 0; step < KK; step++) {
        if (tid == 0) {
            double bv = DBL_MAX; int br = 0;
            for (int r = 0; r < KK; r++)
                if (g_act[r] && g_rv[r] < bv) { bv = g_rv[r]; br = r; }
            const int bc = g_rc[br];
            prow[step] = br; pcol[step] = bc;
            pvalid[step] = (bv < VLARGE * 0.5) ? 1 : 0;
            g_act[br] = 0; consumed[step] = bc;
            const int sstar = bc / SLICE;
            int nd = 0, nr = 0;
            for (int r = 0; r < KK; r++) {
                if (!g_act[r]) continue;
                const int j0 = 2 * sstar;
                bool killed = false;
                if (ccol[r][j0] == bc && cv[r][j0] < DBL_MAX)         { cv[r][j0] = DBL_MAX;     killed = true; }
                if (ccol[r][j0 + 1] == bc && cv[r][j0 + 1] < DBL_MAX) { cv[r][j0 + 1] = DBL_MAX; killed = true; }
                if (killed && cv[r][j0] >= DBL_MAX && cv[r][j0 + 1] >= DBL_MAX) {
                    rlist_r[nr] = r; rlist_s[nr] = sstar; nr++;   // both dead -> rescan slice
                }
                if (g_rc[r] == bc) dlist[nd++] = r;               // cached best consumed -> re-min
            }
            s_ndirty = nd; s_nresc = nr;
        }
        __syncthreads();

        // rare: cooperative rescan of an exhausted (row, slice) pair
        const int nresc = s_nresc;
        for (int i = 0; i < nresc; i++) {
            const int r = rlist_r[i], sl = rlist_s[i];
            const float ffs = (float)g_fs[r], ffe = (float)g_fe[r];
            const int cl = g_cls[r], pres = g_pres[r];
            float v1 = FLT_MAX, v2 = FLT_MAX; int c1 = 0x7fffffff, c2 = 0x7fffffff;
            const int basec = sl * SLICE;
            const int ncons = step + 1;
            for (int t = tid; t < SLICE; t += TPM) {
                const int n = basec + t;
                bool used = false;
                for (int u = 0; u < ncons; u++) if (consumed[u] == n) used = true;
                if (used) continue;
                float cost;
                if (!pres) {
                    cost = (float)VLARGE;
                } else {
                    const float s  = sigf(ps[n]);
                    const float e  = sigf(pe[n]);
                    const float q0 = sigf(pc[2 * n]), q1 = sigf(pc[2 * n + 1]);
                    const float d0 = s - ffs, d1 = e - ffe;
                    const float sc = (cl == 0) ? q0 : q1;
                    cost = d0 * d0 + d1 * d1 + (q0 * q0 + q1 * q1 - 2.0f * sc + 1.0f);
                }
                if (lexlt_f(cost, n, v2, c2)) {
                    if (lexlt_f(cost, n, v1, c1)) { v2 = v1; c2 = c1; v1 = cost; c1 = n; }
                    else                          { v2 = cost; c2 = n; }
                }
            }
            #pragma unroll
            for (int off = 1; off < 64; off <<= 1) {
                float ov1 = __shfl_xor(v1, off, 64); int oc1 = __shfl_xor(c1, off, 64);
                float ov2 = __shfl_xor(v2, off, 64); int oc2 = __shfl_xor(c2, off, 64);
                merge_top2(v1, c1, v2, c2, ov1, oc1, ov2, oc2);
            }
            if (lane == 0) { w_v1[wid] = v1; w_c1[wid] = c1; w_v2[wid] = v2; w_c2[wid] = c2; }
            __syncthreads();
            if (tid == 0) {
                float m1 = w_v1[0], m2 = w_v2[0]; int mc1 = w_c1[0], mc2 = w_c2[0];
                #pragma unroll
                for (int w = 1; w < TPM / 64; w++)
                    merge_top2(m1, mc1, m2, mc2, w_v1[w], w_c1[w], w_v2[w], w_c2[w]);
                for (int which = 0; which < 2; which++) {
                    const int mc = which ? mc2 : mc1;
                    double cost = DBL_MAX;
                    if (mc != 0x7fffffff) {
                        if (!g_pres[r]) {
                            cost = VLARGE;
                        } else {
                            const double s  = dsig(ps[mc]);
                            const double e  = dsig(pe[mc]);
                            const double q0 = dsig(pc[2 * mc]);
                            const double q1 = dsig(pc[2 * mc + 1]);
                            const double d0 = s - g_fs[r], d1 = e - g_fe[r];
                            const double sc = (g_cls[r] == 0) ? q0 : q1;
                            cost = d0 * d0 + d1 * d1 + (q0 * q0 + q1 * q1 - 2.0 * sc + 1.0);
                        }
                    }
                    cv[r][2 * sl + which] = cost;
                    ccol[r][2 * sl + which] = mc;
                }
            }
            __syncthreads();
        }

        // re-min dirty rows (wave 0)
        if (wid == 0) {
            const int nd = s_ndirty;
            for (int i = 0; i < nd; i++) {
                const int r = dlist[i];
                double v = cv[r][lane]; int c = ccol[r][lane];
                #pragma unroll
                for (int off = 1; off < 64; off <<= 1) {
                    double ov = __shfl_xor(v, off, 64); int oc = __shfl_xor(c, off, 64);
                    if (lexlt_d(ov, oc, v, c)) { v = ov; c = oc; }
                }
                if (lane == 0) { g_rv[r] = v; g_rc[r] = c; }
            }
        }
        __syncthreads();
    }

    // losses over matched pairs, parallel over the K picks
    if (tid < KK) {
        const int stp = tid;
        double loc_s = 0.0, bce_s = 0.0, conf_s = 0.0, m = 0.0;
        if (pvalid[stp]) {
            const int r = prow[stp], cidx = pcol[stp];
            const double ss = dsig(ps[cidx]);
            const double se = dsig(pe[cidx]);
            const double gs = g_fs[r], ge = g_fe[r];
            const double d0 = ss - gs, d1 = se - ge;
            loc_s = d0 * d0 + d1 * d1;

            const double l0 = (double)pc[2 * cidx];
            const double l1 = (double)pc[2 * cidx + 1];
            const double y0 = (g_cls[r] == 0) ? 1.0 : 0.0;
            const double y1 = 1.0 - y0;
            bce_s = y0 * dsoftplus(-l0) + (1.0 - y0) * dsoftplus(l0)
                  + y1 * dsoftplus(-l1) + (1.0 - y1) * dsoftplus(l1);

            const double a1 = fmin(ss, se), b1 = fmax(ss, se);
            const double a2 = fmin(gs, ge), b2 = fmax(gs, ge);
            const double inter = fmax(0.0, fmin(b1, b2) - fmax(a1, a2));
            const double uni   = fmax(1e-8, fmax(b1, b2) - fmin(a1, a2));
            const double iou   = inter / uni;
            const double dcf   = dsig(pcf[cidx]) - iou;
            conf_s = dcf * dcf;
            m = 1.0;
        }
        l_loc[stp] = loc_s; l_bce[stp] = bce_s; l_conf[stp] = conf_s; l_m[stp] = m;
    }
    __syncthreads();
    if (tid == 0) {
        double a = 0, bsum = 0, c = 0, m = 0;
        for (int i = 0; i < KK; i++) { a += l_loc[i]; bsum += l_bce[i]; c += l_conf[i]; m += l_m[i]; }
        partials[b * 4 + 0] = a;
        partials[b * 4 + 1] = bsum;
        partials[b * 4 + 2] = c;
        partials[b * 4 + 3] = m;
    }
}

__global__ void finalize_kernel(const double* __restrict__ partials,
                                float* __restrict__ out, int out_size) {
    const int t = threadIdx.x;  // 64 threads = 1 wave, one per batch
    for (int i = t; i < out_size; i += 64) out[i] = 0.0f;
    double s = partials[t * 4 + 0] + partials[t * 4 + 1] + partials[t * 4 + 2];
    double m = partials[t * 4 + 3];
    for (int off = 32; off > 0; off >>= 1) {
        s += __shfl_down(s, off, 64);
        m += __shfl_down(m, off, 64);
    }
    if (t == 0) {
        const double total = s / (m + 1e-8);
        out[0] = (float)(m > 0.0 ? total : 0.0);
    }
}

extern "C" void kernel_launch(void* const* d_in, const int* in_sizes, int n_in,
                              void* d_out, int out_size, void* d_ws, size_t ws_size,
                              hipStream_t stream) {
    const float* p_start = (const float*)d_in[0];  // (B, N)
    const float* p_end   = (const float*)d_in[1];  // (B, N)
    const float* p_cls   = (const float*)d_in[2];  // (B, N, C)
    const float* p_conf  = (const float*)d_in[3];  // (B, N)
    const float* gt      = (const float*)d_in[4];  // (B, K, 3)

    int4*   cand     = (int4*)d_ws;                                   // B*S*K*16 B = 320 KiB
    double* partials = (double*)((char*)d_ws + (size_t)BB * S_SL * KK * 16);

    scan_kernel<<<dim3(S_SL, BB), TPA, 0, stream>>>(p_start, p_end, p_cls, gt, cand);
    match_kernel<<<BB, TPM, 0, stream>>>(p_start, p_end, p_cls, p_conf, gt, cand, partials);
    finalize_kernel<<<1, 64, 0, stream>>>(partials, (float*)d_out, out_size);
}